// Round 9
// baseline (186.255 us; speedup 1.0000x reference)
//
#include <hip/hip_runtime.h>
#include <hip/hip_bf16.h>

// Problem constants (reference: B,S,E,H,DK = 2,1024,1024,128,8)
#define Bv  2
#define Sv  1024
#define Ev  1024
#define Hv  128
#define DKv 8
#define Mv  (Bv*Sv)

// softmax scale folding: c = log2(e)/sqrt(8) = 0.5100697
// om *= SQC (=sqrt(c)); Wo *= ISQC (=1/sqrt(c)); SQC*ISQC == 1.0f
#define SQC  0.7141916f
#define ISQC 1.4001855f

typedef __attribute__((ext_vector_type(8))) short short8;
typedef __attribute__((ext_vector_type(4))) float f32x4;

static __device__ __forceinline__ short f2b(float f) {
    __hip_bfloat16 h = __float2bfloat16(f);
    return *reinterpret_cast<short*>(&h);
}

// packed f32x2 -> bf16x2 (low = a, high = b), RNE
static __device__ __forceinline__ unsigned cvtpk(float a, float b) {
    unsigned r;
    asm("v_cvt_pk_bf16_f32 %0, %1, %2" : "=v"(r) : "v"(a), "v"(b));
    return r;
}

// hardware exp2 (v_exp_f32)
static __device__ __forceinline__ float hexp2(float x) {
    return __builtin_amdgcn_exp2f(x);
}

// async global->LDS, 16B per lane; LDS dest = wave-uniform base + lane*16
static __device__ __forceinline__ void gload16(const void* g, void* l) {
    __builtin_amdgcn_global_load_lds(
        (const __attribute__((address_space(1))) unsigned int*)g,
        (__attribute__((address_space(3))) unsigned int*)l, 16, 0, 0);
}

// ---------------------------------------------------------------------------
// bf16 MFMA GEMM (NT): C[m,n] = sum_k A[m,k]*W[n,k] (+bias, +epilogue)
// BM=BN=64, BK=64 -> grid (16,32)=512 blocks (2/CU). 4 waves (2x2), wave
// tile 32x32. LDS double-buffered, one barrier per K-step.
// Staging (waves 0-1: A-tile, waves 2-3: W-tile):
//   *F32==1: fp32 source -> reg-stage: dwordx4 loads -> cvt_pk_bf16 (xWSCALE)
//            -> ds_write_b128 at swizzled slot (slot ^ (row&7))  [rule 21]
//   *F32==0: bf16 source -> global_load_lds(16B), source col pre-swizzled
// Read side (verified r8): phys slot = (kk/8 + g) ^ (fragrow&7).
// EPI==0: om = bf16 cos(acc + bq + phi) * SQC, scattered to [B,H,S,DK]
// EPI==1: out = fp32 acc + bo, row-major [M,E]
// ---------------------------------------------------------------------------
template<int AF32, int WF32, int EPI>
__global__ __launch_bounds__(256)
void gemm_bf16(const short* __restrict__ Ab, const float* __restrict__ Af,
               const short* __restrict__ Wb, const float* __restrict__ Wf,
               const float* __restrict__ bias, const float* __restrict__ phi,
               float wscale, void* __restrict__ outv)
{
    __shared__ short As[2][64 * 64];   // 8 KB each
    __shared__ short Bs[2][64 * 64];

    const int t    = threadIdx.x;
    const int w    = t >> 6, lane = t & 63;
    const int c    = lane & 15, g = lane >> 4;
    const int cs   = c & 7;
    const int wr   = w >> 1,  wc = w & 1;
    const int tm   = blockIdx.y * 64, tn = blockIdx.x * 64;
    const int lr   = lane >> 3;                    // gload16: row in 8-row group
    const int lcs  = ((lane & 7) ^ lr) * 8;        // gload16: pre-swizzled col
    const int rsr  = lane >> 1;                    // reg-stage: row 0..31
    const int rsh  = lane & 1;                     // reg-stage: col half

    f32x4 acc[2][2] = {};

    // stage K-step k0 into LDS buffer s
    auto stage = [&](int s, int k0) {
        if (w < 2) {                                   // ---- A tile
            if constexpr (AF32) {
                const int r = w * 32 + rsr;
                const float* gp = &Af[(size_t)(tm + r) * Ev + k0 + rsh * 32];
                float4 f[8];
                #pragma unroll
                for (int i = 0; i < 8; i++) f[i] = ((const float4*)gp)[i];
                short* dst = &As[s][r * 64];
                #pragma unroll
                for (int i = 0; i < 4; i++) {
                    uint4 u = { cvtpk(f[2*i].x,   f[2*i].y),
                                cvtpk(f[2*i].z,   f[2*i].w),
                                cvtpk(f[2*i+1].x, f[2*i+1].y),
                                cvtpk(f[2*i+1].z, f[2*i+1].w) };
                    *(uint4*)&dst[((rsh * 4 + i) ^ (r & 7)) * 8] = u;
                }
            } else {
                #pragma unroll
                for (int j = 0; j < 4; j++) {
                    const int row = w * 32 + j * 8;
                    gload16(&Ab[(size_t)(tm + row + lr) * Ev + k0 + lcs], &As[s][row * 64]);
                }
            }
        } else {                                       // ---- W tile
            if constexpr (WF32) {
                const int r = (w - 2) * 32 + rsr;
                const float* gp = &Wf[(size_t)(tn + r) * Ev + k0 + rsh * 32];
                float4 f[8];
                #pragma unroll
                for (int i = 0; i < 8; i++) f[i] = ((const float4*)gp)[i];
                short* dst = &Bs[s][r * 64];
                #pragma unroll
                for (int i = 0; i < 4; i++) {
                    uint4 u = { cvtpk(f[2*i].x * wscale,   f[2*i].y * wscale),
                                cvtpk(f[2*i].z * wscale,   f[2*i].w * wscale),
                                cvtpk(f[2*i+1].x * wscale, f[2*i+1].y * wscale),
                                cvtpk(f[2*i+1].z * wscale, f[2*i+1].w * wscale) };
                    *(uint4*)&dst[((rsh * 4 + i) ^ (r & 7)) * 8] = u;
                }
            } else {
                #pragma unroll
                for (int j = 0; j < 4; j++) {
                    const int row = (w - 2) * 32 + j * 8;
                    gload16(&Wb[(size_t)(tn + row + lr) * Ev + k0 + lcs], &Bs[s][row * 64]);
                }
            }
        }
    };

    stage(0, 0);
    __syncthreads();

    for (int ks = 0; ks < 16; ks++) {
        const int cur = ks & 1;
        if (ks < 15) stage(cur ^ 1, (ks + 1) * 64);
        #pragma unroll
        for (int kk = 0; kk < 64; kk += 32) {
            const int s0 = ((kk >> 3) + g) ^ cs;   // swizzled read slot
            short8 af[2], bf[2];
            #pragma unroll
            for (int m = 0; m < 2; m++)
                af[m] = *(const short8*)&As[cur][(wr * 32 + m * 16 + c) * 64 + s0 * 8];
            #pragma unroll
            for (int n = 0; n < 2; n++)
                bf[n] = *(const short8*)&Bs[cur][(wc * 32 + n * 16 + c) * 64 + s0 * 8];
            #pragma unroll
            for (int m = 0; m < 2; m++)
                #pragma unroll
                for (int n = 0; n < 2; n++)
                    acc[m][n] = __builtin_amdgcn_mfma_f32_16x16x32_bf16(af[m], bf[n], acc[m][n], 0, 0, 0);
        }
        __syncthreads();
    }

    // epilogue: D layout row = 4*(lane>>4)+reg, col = lane&15
    #pragma unroll
    for (int i = 0; i < 2; i++) {
        #pragma unroll
        for (int j = 0; j < 2; j++) {
            const int n = tn + wc * 32 + j * 16 + c;
            #pragma unroll
            for (int r = 0; r < 4; r++) {
                const int m = tm + wr * 32 + i * 16 + 4 * g + r;
                const float v = acc[i][j][r];
                if (EPI == 0) {
                    float q = __cosf(v + bias[n] + phi[n]) * SQC;
                    const int bb = m >> 10, ss = m & (Sv - 1);
                    const int hh = n >> 3,  dd = n & (DKv - 1);
                    ((short*)outv)[(((size_t)bb * Hv + hh) * Sv + ss) * DKv + dd] = f2b(q);
                } else {
                    ((float*)outv)[(size_t)m * Ev + n] = v + bias[n];
                }
            }
        }
    }
}

// ---------------------------------------------------------------------------
// MFMA flash attention (r6/r8 verified structure). Swapped-QK^T form.
// Block = one (b,h) x 64 q-rows, 4 waves x 16 q each. No max pass
// (om pre-scaled by sqrt(c): exp2 arg <= 4.08 -> p <= 17, bf16-safe).
// p = exp2(s) directly -- scale folded into om at GEMM1 epilogue.
// ---------------------------------------------------------------------------
__global__ __launch_bounds__(256)
void attn_mfma(const short* __restrict__ om, short* __restrict__ ctx)
{
    __shared__ short K_lds[Sv * DKv];        // [k][d]        16 KB
    __shared__ short Vt[DKv * 1032];         // [d][k] padded 16.5 KB
    __shared__ short P_lds[4][16][40];       // per-wave [q][k] padded, 5 KB

    const int t  = threadIdx.x;
    const int bh = blockIdx.x;
    const short* base = om + (size_t)bh * (Sv * DKv);

    #pragma unroll
    for (int r = 0; r < 4; r++) {
        const int k = r * 256 + t;
        int4 row = ((const int4*)base)[k];
        ((int4*)K_lds)[k] = row;
        union { int4 v; short s[8]; } u; u.v = row;
        #pragma unroll
        for (int d = 0; d < 8; d++) Vt[d * 1032 + k] = u.s[d];
    }
    __syncthreads();

    const int w = t >> 6, lane = t & 63;
    const int c = lane & 15, g = lane >> 4;
    const int q0 = blockIdx.y * 64 + w * 16;

    // Q as B-operand: B[k][q=c] = Q[q][k], k<8 valid (g==0 lanes)
    short8 qf = {};
    if (g == 0) qf = *(const short8*)&K_lds[(q0 + c) * 8];

    f32x4 ctx_acc = {0.f, 0.f, 0.f, 0.f};
    float lsum = 0.f;

    for (int kt = 0; kt < Sv; kt += 32) {
        short8 kf0 = {}, kf1 = {};
        if (g == 0) {
            kf0 = *(const short8*)&K_lds[(kt +      c) * 8];
            kf1 = *(const short8*)&K_lds[(kt + 16 + c) * 8];
        }
        const f32x4 z = {0.f, 0.f, 0.f, 0.f};
        f32x4 s0 = __builtin_amdgcn_mfma_f32_16x16x32_bf16(kf0, qf, z, 0, 0, 0);
        f32x4 s1 = __builtin_amdgcn_mfma_f32_16x16x32_bf16(kf1, qf, z, 0, 0, 0);

        // p = exp2(s); scale pre-folded into om
        float p[8];
        #pragma unroll
        for (int r = 0; r < 4; r++) {
            p[r]     = hexp2(s0[r]);
            p[4 + r] = hexp2(s1[r]);
        }
        lsum += ((p[0] + p[1]) + (p[2] + p[3])) + ((p[4] + p[5]) + (p[6] + p[7]));

        // P[q=c][key]: s0 -> keys 4g..4g+3, s1 -> keys 16+4g..16+4g+3
        uint2 w0, w1;
        w0.x = cvtpk(p[0], p[1]); w0.y = cvtpk(p[2], p[3]);
        w1.x = cvtpk(p[4], p[5]); w1.y = cvtpk(p[6], p[7]);
        *(uint2*)&P_lds[w][c][4 * g]      = w0;
        *(uint2*)&P_lds[w][c][16 + 4 * g] = w1;

        // PV: A = P[q=c][8g..8g+7] (b128), B = V[k][d] via Vt rows
        short8 pf = *(const short8*)&P_lds[w][c][8 * g];
        short8 vf = {};
        if (c < 8) vf = *(const short8*)&Vt[c * 1032 + kt + 8 * g];
        ctx_acc = __builtin_amdgcn_mfma_f32_16x16x32_bf16(pf, vf, ctx_acc, 0, 0, 0);
    }

    // reduce lsum across lanes sharing q (=c): lanes c, c+16, c+32, c+48
    lsum += __shfl_xor(lsum, 16);
    lsum += __shfl_xor(lsum, 32);
    float L[4];
    #pragma unroll
    for (int r = 0; r < 4; r++) L[r] = __shfl(lsum, 4 * g + r);

    if (c < 8) {
        const int b = bh >> 7, h = bh & (Hv - 1);
        #pragma unroll
        for (int r = 0; r < 4; r++) {
            const int q = q0 + 4 * g + r;
            ctx[((size_t)(b * Sv + q)) * Ev + h * DKv + c] = f2b(ctx_acc[r] / L[r]);
        }
    }
}

// ---------------------------------------------------------------------------
extern "C" void kernel_launch(void* const* d_in, const int* in_sizes, int n_in,
                              void* d_out, int out_size, void* d_ws, size_t ws_size,
                              hipStream_t stream)
{
    const float* x   = (const float*)d_in[0];
    const float* Wq  = (const float*)d_in[1];
    const float* bq  = (const float*)d_in[2];
    // d_in[3..6] = Wk, bk, Wv, bv -- dead in the reference math.
    const float* phi = (const float*)d_in[7];
    const float* Wo  = (const float*)d_in[8];
    const float* bo  = (const float*)d_in[9];
    float* out = (float*)d_out;

    char* ws = (char*)d_ws;
    short* ctx = (short*)ws;                       // [B,S,E] bf16 (* SQC), 4 MB
    short* om  = (short*)(ws + (4 << 20));         // [B,H,S,DK] bf16 (* SQC), 4 MB

    const dim3 gg(Ev / 64, Mv / 64);               // (16, 32) = 512 blocks
    gemm_bf16<1, 1, 0><<<gg, 256, 0, stream>>>(nullptr, x, nullptr, Wq,
                                               bq, phi, 1.0f, (void*)om);
    attn_mfma<<<dim3(Bv * Hv, Sv / 64), 256, 0, stream>>>(om, ctx);
    gemm_bf16<0, 1, 1><<<gg, 256, 0, stream>>>(ctx, nullptr, nullptr, Wo,
                                               bo, nullptr, ISQC, (void*)out);
}

// Round 10
// 168.290 us; speedup vs baseline: 1.1067x; 1.1067x over previous
//
#include <hip/hip_runtime.h>
#include <hip/hip_bf16.h>

// Problem constants (reference: B,S,E,H,DK = 2,1024,1024,128,8)
#define Bv  2
#define Sv  1024
#define Ev  1024
#define Hv  128
#define DKv 8
#define Mv  (Bv*Sv)

// softmax scale folding: c = log2(e)/sqrt(8) = 0.5100697
// om *= SQC (=sqrt(c)) at GEMM1 epilogue; Wo *= ISQC at cvt; SQC*ISQC == 1
#define SQC  0.7141916f
#define ISQC 1.4001855f

typedef __attribute__((ext_vector_type(8))) short short8;
typedef __attribute__((ext_vector_type(4))) float f32x4;

static __device__ __forceinline__ short f2b(float f) {
    __hip_bfloat16 h = __float2bfloat16(f);
    return *reinterpret_cast<short*>(&h);
}

// packed f32x2 -> bf16x2 (low = a, high = b), RNE
static __device__ __forceinline__ unsigned cvtpk(float a, float b) {
    unsigned r;
    asm("v_cvt_pk_bf16_f32 %0, %1, %2" : "=v"(r) : "v"(a), "v"(b));
    return r;
}

// hardware exp2 (v_exp_f32)
static __device__ __forceinline__ float hexp2(float x) {
    return __builtin_amdgcn_exp2f(x);
}

// async global->LDS, 16B per lane; LDS dest = wave-uniform base + lane*16
static __device__ __forceinline__ void gload16(const void* g, void* l) {
    __builtin_amdgcn_global_load_lds(
        (const __attribute__((address_space(1))) unsigned int*)g,
        (__attribute__((address_space(3))) unsigned int*)l, 16, 0, 0);
}

// ---------------------------------------------------------------------------
// fused fp32 -> bf16 cast: x (1024 blk), Wq (512 blk), Wo*ISQC (512 blk)
// ---------------------------------------------------------------------------
__global__ __launch_bounds__(256)
void cvt_all(const float* __restrict__ x, const float* __restrict__ wq,
             const float* __restrict__ wo, short* __restrict__ xb,
             short* __restrict__ wqb, short* __restrict__ wob)
{
    const int b = blockIdx.x;
    const float* src; short* dst; int i; float sc = 1.0f;
    if (b < 1024)      { src = x;  dst = xb;  i = b * 256 + threadIdx.x; }
    else if (b < 1536) { src = wq; dst = wqb; i = (b - 1024) * 256 + threadIdx.x; }
    else               { src = wo; dst = wob; i = (b - 1536) * 256 + threadIdx.x; sc = ISQC; }
    float4 a = ((const float4*)src)[2 * i];
    float4 c = ((const float4*)src)[2 * i + 1];
    uint4 o;
    o.x = cvtpk(a.x * sc, a.y * sc); o.y = cvtpk(a.z * sc, a.w * sc);
    o.z = cvtpk(c.x * sc, c.y * sc); o.w = cvtpk(c.z * sc, c.w * sc);
    ((uint4*)dst)[i] = o;
}

// ---------------------------------------------------------------------------
// bf16 MFMA GEMM (NT), r8-verified structure: BM=BN=64, BK=64, 512 blocks
// (2/CU), 4 waves, dbuf LDS (one barrier/K-step), gload16 with pre-swizzled
// source col; read slot = (kk/8+g)^(fragrow&7)  [rule 21, verified r8].
// NEW: 1D grid + bijective XCD swizzle (each XCD chunk: 4 A-panels x all-n,
// 2.5 MB <= 4 MB L2/XCD).
// EPI==0: om = bf16 cos(acc+bq+phi)*SQC scattered to [B,H,S,DK]
// EPI==1: out = fp32 acc + bo, row-major [M,E]
// ---------------------------------------------------------------------------
template<int EPI>
__global__ __launch_bounds__(256)
void gemm_bf16(const short* __restrict__ A, const short* __restrict__ W,
               const float* __restrict__ bias, const float* __restrict__ phi,
               void* __restrict__ outv)
{
    __shared__ short As[2][64 * 64];   // 8 KB each
    __shared__ short Bs[2][64 * 64];

    const int t    = threadIdx.x;
    const int w    = t >> 6, lane = t & 63;
    const int c    = lane & 15, g = lane >> 4;
    const int cs   = c & 7;
    const int wr   = w >> 1,  wc = w & 1;
    const int bid  = blockIdx.x;
    const int swz  = (bid & 7) * 64 + (bid >> 3);   // XCD-aware, bijective (512%8==0)
    const int tn   = (swz & 15) * 64, tm = (swz >> 4) * 64;
    const int lr   = lane >> 3;                    // row in 8-row group
    const int lcs  = ((lane & 7) ^ lr) * 8;        // pre-swizzled source col

    f32x4 acc[2][2] = {};

    #define STAGE(s, k0)                                                        \
        _Pragma("unroll")                                                       \
        for (int j = 0; j < 2; j++) {                                           \
            const int row = w * 16 + j * 8;                                     \
            gload16(&A[(size_t)(tm + row + lr) * Ev + (k0) + lcs], &As[s][row * 64]); \
            gload16(&W[(size_t)(tn + row + lr) * Ev + (k0) + lcs], &Bs[s][row * 64]); \
        }

    STAGE(0, 0)
    __syncthreads();

    for (int ks = 0; ks < 16; ks++) {
        const int cur = ks & 1;
        if (ks < 15) { STAGE(cur ^ 1, (ks + 1) * 64) }
        #pragma unroll
        for (int kk = 0; kk < 64; kk += 32) {
            const int s0 = ((kk >> 3) + g) ^ cs;   // swizzled read slot
            short8 af[2], bf[2];
            #pragma unroll
            for (int m = 0; m < 2; m++)
                af[m] = *(const short8*)&As[cur][(wr * 32 + m * 16 + c) * 64 + s0 * 8];
            #pragma unroll
            for (int n = 0; n < 2; n++)
                bf[n] = *(const short8*)&Bs[cur][(wc * 32 + n * 16 + c) * 64 + s0 * 8];
            #pragma unroll
            for (int m = 0; m < 2; m++)
                #pragma unroll
                for (int n = 0; n < 2; n++)
                    acc[m][n] = __builtin_amdgcn_mfma_f32_16x16x32_bf16(af[m], bf[n], acc[m][n], 0, 0, 0);
        }
        __syncthreads();
    }

    // epilogue: D layout row = 4*(lane>>4)+reg, col = lane&15
    #pragma unroll
    for (int i = 0; i < 2; i++) {
        #pragma unroll
        for (int j = 0; j < 2; j++) {
            const int n = tn + wc * 32 + j * 16 + c;
            #pragma unroll
            for (int r = 0; r < 4; r++) {
                const int m = tm + wr * 32 + i * 16 + 4 * g + r;
                const float v = acc[i][j][r];
                if (EPI == 0) {
                    float q = __cosf(v + bias[n] + phi[n]) * SQC;
                    const int bb = m >> 10, ss = m & (Sv - 1);
                    const int hh = n >> 3,  dd = n & (DKv - 1);
                    ((short*)outv)[(((size_t)bb * Hv + hh) * Sv + ss) * DKv + dd] = f2b(q);
                } else {
                    ((float*)outv)[(size_t)m * Ev + n] = v + bias[n];
                }
            }
        }
    }
    #undef STAGE
}

// ---------------------------------------------------------------------------
// MFMA flash attention (r6/r8/r9-verified skeleton). Swapped-QK^T, no max
// pass (om pre-scaled by sqrt(c): exp2 arg <= 4.08, p <= 17 bf16-safe).
// NEW vs r9:
//  * zero-page pointers: masked lanes (g!=0 / c>8) read a 16B LDS zero page
//    -> no per-iter exec-mask save/restore or cndmask zeroing
//  * L computed INSIDE the PV MFMA: c==8 lanes feed a ones-column as
//    V[:,8], so D[:,8] = row-sum(P) = L. Deletes lsum adds + shfl tree.
//  * split launch (qbase): 2 dispatches of 8 q-tiles -> GEMMs become
//    visible in rocprof top-5.
// ---------------------------------------------------------------------------
__global__ __launch_bounds__(256)
void attn_mfma(const short* __restrict__ om, short* __restrict__ ctx, int qbase)
{
    __shared__ short K_lds[Sv * DKv];        // [k][d]        16 KB
    __shared__ short Vt[DKv * 1032];         // [d][k] padded 16.5 KB
    __shared__ short P_lds[4][16][40];       // per-wave [q][k] padded, 5 KB
    __shared__ __align__(16) short zpage[8]; // 16B zeros
    __shared__ __align__(16) short opage[8]; // 16B bf16 1.0

    const int t  = threadIdx.x;
    const int bh = blockIdx.x;
    const short* base = om + (size_t)bh * (Sv * DKv);

    if (t < 8) zpage[t] = 0;
    else if (t < 16) opage[t - 8] = 0x3F80;   // bf16 1.0

    #pragma unroll
    for (int r = 0; r < 4; r++) {
        const int k = r * 256 + t;
        int4 row = ((const int4*)base)[k];
        ((int4*)K_lds)[k] = row;
        union { int4 v; short s[8]; } u; u.v = row;
        #pragma unroll
        for (int d = 0; d < 8; d++) Vt[d * 1032 + k] = u.s[d];
    }
    __syncthreads();

    const int w = t >> 6, lane = t & 63;
    const int c = lane & 15, g = lane >> 4;
    const int q0 = qbase + blockIdx.y * 64 + w * 16;

    // Q as B-operand: B[k][q=c] = Q[q][k], k<8 valid (g==0 lanes)
    short8 qf = {};
    if (g == 0) qf = *(const short8*)&K_lds[(q0 + c) * 8];

    // per-lane walking pointers; masked lanes pinned to zero/ones pages
    const short* kp0 = (g == 0) ? &K_lds[c * 8]        : zpage;
    const short* kp1 = (g == 0) ? &K_lds[(16 + c) * 8] : zpage;
    const int   kadv = (g == 0) ? 32 * 8 : 0;
    const short* vp  = (c < 8) ? &Vt[c * 1032 + 8 * g] : (c == 8 ? opage : zpage);
    const int   vadv = (c < 8) ? 32 : 0;

    f32x4 acc = {0.f, 0.f, 0.f, 0.f};
    const f32x4 z = {0.f, 0.f, 0.f, 0.f};

    for (int kt = 0; kt < Sv; kt += 32) {
        short8 kf0 = *(const short8*)kp0;  kp0 += kadv;
        short8 kf1 = *(const short8*)kp1;  kp1 += kadv;
        f32x4 s0 = __builtin_amdgcn_mfma_f32_16x16x32_bf16(kf0, qf, z, 0, 0, 0);
        f32x4 s1 = __builtin_amdgcn_mfma_f32_16x16x32_bf16(kf1, qf, z, 0, 0, 0);

        // p = exp2(s) (scale pre-folded into om); pack straight to bf16
        uint2 w0, w1;
        w0.x = cvtpk(hexp2(s0[0]), hexp2(s0[1]));
        w0.y = cvtpk(hexp2(s0[2]), hexp2(s0[3]));
        w1.x = cvtpk(hexp2(s1[0]), hexp2(s1[1]));
        w1.y = cvtpk(hexp2(s1[2]), hexp2(s1[3]));
        *(uint2*)&P_lds[w][c][4 * g]      = w0;
        *(uint2*)&P_lds[w][c][16 + 4 * g] = w1;

        // PV (+ ones-column): A = P[q=c][8g..8g+7], B[k][d]; D[:,8] = L
        short8 pf = *(const short8*)&P_lds[w][c][8 * g];
        short8 vf = *(const short8*)vp;  vp += vadv;
        acc = __builtin_amdgcn_mfma_f32_16x16x32_bf16(pf, vf, acc, 0, 0, 0);
    }

    // L for rows 4g+r lives in lane (c==8, same g), reg r
    float L[4];
    #pragma unroll
    for (int r = 0; r < 4; r++) L[r] = __shfl(acc[r], (lane & 48) | 8);

    if (c < 8) {
        const int b = bh >> 7, h = bh & (Hv - 1);
        #pragma unroll
        for (int r = 0; r < 4; r++) {
            const int q = q0 + 4 * g + r;
            ctx[((size_t)(b * Sv + q)) * Ev + h * DKv + c] = f2b(acc[r] / L[r]);
        }
    }
}

// ---------------------------------------------------------------------------
extern "C" void kernel_launch(void* const* d_in, const int* in_sizes, int n_in,
                              void* d_out, int out_size, void* d_ws, size_t ws_size,
                              hipStream_t stream)
{
    const float* x   = (const float*)d_in[0];
    const float* Wq  = (const float*)d_in[1];
    const float* bq  = (const float*)d_in[2];
    // d_in[3..6] = Wk, bk, Wv, bv -- dead in the reference math.
    const float* phi = (const float*)d_in[7];
    const float* Wo  = (const float*)d_in[8];
    const float* bo  = (const float*)d_in[9];
    float* out = (float*)d_out;

    char* ws = (char*)d_ws;
    short* xb  = (short*)ws;                       // [M,E] bf16, 4 MB
    short* ctx = xb;                               // alias: written after xb's last read
    short* om  = (short*)(ws + (4 << 20));         // [B,H,S,DK] bf16 (*SQC), 4 MB
    short* Wqb = (short*)(ws + (8 << 20));         // [E,E] bf16, 2 MB
    short* Wob = (short*)(ws + (10 << 20));        // [E,E] bf16 (*ISQC), 2 MB

    cvt_all<<<dim3(2048), 256, 0, stream>>>(x, Wq, Wo, xb, Wqb, Wob);

    gemm_bf16<0><<<dim3(512), 256, 0, stream>>>(xb, Wqb, bq, phi, (void*)om);
    attn_mfma<<<dim3(Bv * Hv, 8), 256, 0, stream>>>(om, ctx, 0);
    attn_mfma<<<dim3(Bv * Hv, 8), 256, 0, stream>>>(om, ctx, 512);
    gemm_bf16<1><<<dim3(512), 256, 0, stream>>>(ctx, Wob, bo, nullptr, (void*)out);
}